// Round 10
// baseline (270.589 us; speedup 1.0000x reference)
//
#include <hip/hip_runtime.h>
#include <hip/hip_bf16.h>
#include <math.h>

#define NB 1024
#define NC 100000
#define ND 512
#define SSCALE 64.0f
#define MMARGIN 0.5f

#define BM 256
#define BN 256
#define BK 64
#define NKS (ND / BK)                // 8 K-tiles
#define NRT (NB / BM)                // 4 row tiles
#define NCT ((NC + BN - 1) / BN)     // 391 col tiles
#define GRIDSZ (NRT * NCT)           // 1564
#define NCPAD (NCT * BN)             // 100096 padded classes (Wbf rows)

#define ABUF  32768                  // A: 2 x 32KB (256 rows x 128B)
#define BBASE 65536                  // B: 2 x 32KB (256 cls x 128B)

typedef __bf16 bf16x8 __attribute__((ext_vector_type(8)));
typedef float f32x4 __attribute__((ext_vector_type(4)));

__device__ __forceinline__ void gload_lds16(const void* g, void* l) {
    __builtin_amdgcn_global_load_lds(
        (const __attribute__((address_space(1))) unsigned int*)g,
        (__attribute__((address_space(3))) unsigned int*)l, 16, 0, 0);
}

// ---------------------------------------------------------------------------
// ws layout: xnb bf16[1024][512] @0 (1MB); sums f32[1024] @1MB; tgt f32[1024];
//            Wbf bf16[100096][512] @1056768 (102.5MB) when ws_size permits.
// ---------------------------------------------------------------------------

__global__ void prep_kernel(const float* __restrict__ x, __bf16* __restrict__ xnb) {
    const int row = blockIdx.x;
    const int tid = threadIdx.x;
    const float2 v = *reinterpret_cast<const float2*>(x + (size_t)row * ND + tid * 2);
    float ss = v.x * v.x + v.y * v.y;
#pragma unroll
    for (int m = 1; m < 64; m <<= 1) ss += __shfl_xor(ss, m);
    __shared__ float wsum[4];
    if ((tid & 63) == 0) wsum[tid >> 6] = ss;
    __syncthreads();
    const float tot = wsum[0] + wsum[1] + wsum[2] + wsum[3];
    const float inv = 1.0f / fmaxf(sqrtf(tot), 1e-12f);
    __bf16* dst = xnb + (size_t)row * ND + tid * 2;
    dst[0] = (__bf16)(v.x * inv);
    dst[1] = (__bf16)(v.y * inv);
}

__global__ void target_kernel(const __bf16* __restrict__ xnb, const float* __restrict__ Wg,
                              const int* __restrict__ labels, float* __restrict__ tgt) {
    const int wid  = threadIdx.x >> 6;
    const int lane = threadIdx.x & 63;
    const int row  = blockIdx.x * 4 + wid;
    const int lab  = labels[row];
    const int k    = lane * 8;
    const bf16x8 xv = *reinterpret_cast<const bf16x8*>(xnb + (size_t)row * ND + k);
    const float* wr = Wg + (size_t)lab * ND + k;
    const float4 w0 = *reinterpret_cast<const float4*>(wr);
    const float4 w1 = *reinterpret_cast<const float4*>(wr + 4);
    float s = (float)xv[0] * w0.x + (float)xv[1] * w0.y + (float)xv[2] * w0.z + (float)xv[3] * w0.w
            + (float)xv[4] * w1.x + (float)xv[5] * w1.y + (float)xv[6] * w1.z + (float)xv[7] * w1.w;
#pragma unroll
    for (int m = 1; m < 64; m <<= 1) s += __shfl_xor(s, m);
    if (lane == 0) tgt[row] = s;
}

// W fp32 -> bf16 once; rows NC..NCPAD zeroed. 25024 blocks x 256 thr x 8 elems.
__global__ void cvtw_kernel(const float* __restrict__ W, __bf16* __restrict__ Wbf) {
    const size_t gid = (size_t)blockIdx.x * 256 + threadIdx.x;
    bf16x8 h = {};
    if (gid * 8 < (size_t)NC * ND) {
        const float4 v0 = *reinterpret_cast<const float4*>(W + gid * 8);
        const float4 v1 = *reinterpret_cast<const float4*>(W + gid * 8 + 4);
        h[0] = (__bf16)v0.x; h[1] = (__bf16)v0.y; h[2] = (__bf16)v0.z; h[3] = (__bf16)v0.w;
        h[4] = (__bf16)v1.x; h[5] = (__bf16)v1.y; h[6] = (__bf16)v1.z; h[7] = (__bf16)v1.w;
    }
    *reinterpret_cast<bf16x8*>(Wbf + gid * 8) = h;
}

// 256x256x64 GEMM, m201-style 4-phase-per-K-tile schedule, 8 waves (2 row x
// 4 col groups, wave tile 128x64, acc 8x4). Both operands bf16 via gload_lds
// w16 with pre-swizzled source (proven conflict-free). Per phase: {ds_read
// frags; 2-3 stage issues; s_barrier; lgkmcnt(0)+sched_barrier; setprio(1);
// 16 MFMA; setprio(0); s_barrier}. b-frags live in regs across the two
// row-half phases (25% fewer LDS reads). Tile-end barrier drains vmcnt with
// >=2 phases of cover. 128KB LDS -> 1 block/CU (the m201 design point).
__global__ __launch_bounds__(512, 2) void gemm_exp_kernel(const __bf16* __restrict__ xnb,
                                                          const __bf16* __restrict__ Wbf,
                                                          float* __restrict__ sums) {
    __shared__ char lds[131072];
    const int tid  = threadIdx.x;
    const int wid  = tid >> 6;
    const int lane = tid & 63;
    const int l15  = lane & 15;
    const int lhi  = lane >> 4;
    const int wr   = wid >> 2;       // 0..1 : 128-row group
    const int wc   = wid & 3;        // 0..3 : 64-col group

    // bijective XCD swizzle (m204): 1564 = 8*195 + 4
    const int xcd = blockIdx.x & 7, idx = blockIdx.x >> 3;
    const int q = GRIDSZ >> 3, rr = GRIDSZ & 7;
    const int wgid = (xcd < rr ? xcd * (q + 1) : rr * (q + 1) + (xcd - rr) * q) + idx;
    const int rt = wgid & 3;         // 4 consecutive logicals share ct -> W panel L2-resident
    const int ct = wgid >> 2;
    const int r0 = rt * BM;
    const int c0 = ct * BN;

    // ---- hoisted LDS fragment offsets: addr = base + (off ^ (kk<<6)) ----
    int aoff[2][4], boff[4];
#pragma unroll
    for (int ih = 0; ih < 2; ++ih)
#pragma unroll
        for (int i = 0; i < 4; ++i) {
            const int r = wr * 128 + (ih * 4 + i) * 16 + l15;
            aoff[ih][i] = r * 128 + ((lhi ^ (r & 3)) << 4) + (((r >> 2) & 1) << 6);
        }
#pragma unroll
    for (int j = 0; j < 4; ++j) {
        const int cls = wc * 64 + j * 16 + l15;
        boff[j] = cls * 128 + ((lhi ^ (cls & 3)) << 4) + (((cls >> 2) & 1) << 6);
    }
    // ---- hoisted staging source offsets (pre-swizzled, rule 21) ----
    size_t aoffg[4], boffg[4];
#pragma unroll
    for (int s = 0; s < 4; ++s) {
        const int lin = s * 8192 + wid * 1024 + lane * 16;
        const int row = lin >> 7;
        const int ck  = (lin >> 4) & 7;
        const int sw  = (ck ^ (row & 7)) << 4;
        aoffg[s] = (size_t)(r0 + row) * 1024 + sw;
        boffg[s] = (size_t)(c0 + row) * 1024 + sw;
    }

    auto stA = [&](int t, int nb, int s) {
        gload_lds16((const char*)xnb + aoffg[s] + (size_t)t * 128,
                    lds + nb * ABUF + s * 8192 + wid * 1024);
    };
    auto stB = [&](int t, int nb, int s) {
        gload_lds16((const char*)Wbf + boffg[s] + (size_t)t * 128,
                    lds + BBASE + nb * ABUF + s * 8192 + wid * 1024);
    };
    auto readA = [&](int ab, const int (&ao)[4], int kk, bf16x8 (&a)[4]) {
#pragma unroll
        for (int i = 0; i < 4; ++i)
            a[i] = *reinterpret_cast<const bf16x8*>(lds + ab + (ao[i] ^ (kk << 6)));
    };
    auto readB = [&](int bb, int kk, bf16x8 (&b)[4]) {
#pragma unroll
        for (int j = 0; j < 4; ++j)
            b[j] = *reinterpret_cast<const bf16x8*>(lds + bb + (boff[j] ^ (kk << 6)));
    };

    f32x4 acc[8][4] = {};

#define MFMA16(AC, A, B)                                                      \
    _Pragma("unroll")                                                         \
    for (int i = 0; i < 4; ++i)                                               \
        _Pragma("unroll")                                                     \
        for (int j = 0; j < 4; ++j)                                           \
            (AC)[i][j] = __builtin_amdgcn_mfma_f32_16x16x32_bf16(             \
                (A)[i], (B)[j], (AC)[i][j], 0, 0, 0);

#define SYNC_PRE                                                              \
    __builtin_amdgcn_s_barrier();                                             \
    asm volatile("s_waitcnt lgkmcnt(0)" ::: "memory");                        \
    __builtin_amdgcn_sched_barrier(0);                                        \
    __builtin_amdgcn_s_setprio(1);

#define SYNC_POST                                                             \
    __builtin_amdgcn_s_setprio(0);                                            \
    __builtin_amdgcn_s_barrier();

    // ---- prologue: stage tile 0 into buffer 0, full drain ----
#pragma unroll
    for (int s = 0; s < 4; ++s) { stA(0, 0, s); stB(0, 0, s); }
    asm volatile("s_waitcnt vmcnt(0) lgkmcnt(0)\ns_barrier" ::: "memory");

#pragma unroll 1
    for (int kt = 0; kt < NKS; ++kt) {
        const int cur = kt & 1, nxt = cur ^ 1;
        const int ab = cur * ABUF, bb = BBASE + cur * ABUF;
        const bool pf = (kt + 1) < NKS;
        bf16x8 afr[4], bfr[4];

        // phase 0: (ih0, kk0) — read b(kk0)+a; issue A s0,s1
        readB(bb, 0, bfr);
        readA(ab, aoff[0], 0, afr);
        if (pf) { stA(kt + 1, nxt, 0); stA(kt + 1, nxt, 1); }
        SYNC_PRE; MFMA16(&acc[0], afr, bfr); SYNC_POST;

        // phase 1: (ih1, kk0) — reuse b; issue A s2,s3 + B s0
        readA(ab, aoff[1], 0, afr);
        if (pf) { stA(kt + 1, nxt, 2); stA(kt + 1, nxt, 3); stB(kt + 1, nxt, 0); }
        SYNC_PRE; MFMA16(&acc[4], afr, bfr); SYNC_POST;

        // phase 2: (ih0, kk1) — read b(kk1)+a; issue B s1,s2,s3
        readB(bb, 1, bfr);
        readA(ab, aoff[0], 1, afr);
        if (pf) { stB(kt + 1, nxt, 1); stB(kt + 1, nxt, 2); stB(kt + 1, nxt, 3); }
        SYNC_PRE; MFMA16(&acc[0], afr, bfr); SYNC_POST;

        // phase 3: (ih1, kk1) — reuse b; tile-end drain barrier
        readA(ab, aoff[1], 1, afr);
        SYNC_PRE; MFMA16(&acc[4], afr, bfr);
        __builtin_amdgcn_s_setprio(0);
        asm volatile("s_waitcnt vmcnt(0) lgkmcnt(0)\ns_barrier" ::: "memory");
    }

    // ---- epilogue: exp + row-sum over this wave's 64 cols + atomic ----
#pragma unroll
    for (int i = 0; i < 8; ++i) {
#pragma unroll
        for (int r = 0; r < 4; ++r) {
            float v = 0.f;
#pragma unroll
            for (int j = 0; j < 4; ++j) {
                const int c = c0 + wc * 64 + j * 16 + l15;
                v += (c < NC) ? __expf(SSCALE * acc[i][j][r]) : 0.f;
            }
            v += __shfl_xor(v, 1);
            v += __shfl_xor(v, 2);
            v += __shfl_xor(v, 4);
            v += __shfl_xor(v, 8);
            if (l15 == 0) {
                const int row = r0 + wr * 128 + i * 16 + lhi * 4 + r;
                atomicAdd(&sums[row], v);
            }
        }
    }
#undef MFMA16
#undef SYNC_PRE
#undef SYNC_POST
}

// Fallback (ws too small for Wbf): R2-family 2-barrier kernel, fp32 B in-loop.
__global__ __launch_bounds__(256, 2) void gemm_exp_fb(const __bf16* __restrict__ xnb,
                                                      const float* __restrict__ Wg,
                                                      float* __restrict__ sums) {
    __shared__ char lds[65536];
    const int tid  = threadIdx.x;
    const int wid  = tid >> 6;
    const int lane = tid & 63;
    const int l15  = lane & 15;
    const int lhi  = lane >> 4;
    const int wr   = wid >> 1;
    const int wc   = wid & 1;
    const int logical = (blockIdx.x & 7) * (6256 / 8) + (blockIdx.x >> 3);
    const int r0 = (logical & 7) * 128;
    const int c0 = (logical >> 3) * 128;
    const int bcls = tid >> 3;
    const int bqp  = tid & 7;
    float4 bw[8];
    auto loadB = [&](int t) {
#pragma unroll
        for (int l = 0; l < 4; ++l) {
            const int cls = l * 32 + bcls;
            const float* src = Wg + (size_t)(c0 + cls) * ND + t * 64 + bqp * 8;
            if (c0 + cls < NC) {
                bw[l * 2]     = *reinterpret_cast<const float4*>(src);
                bw[l * 2 + 1] = *reinterpret_cast<const float4*>(src + 4);
            } else {
                bw[l * 2] = make_float4(0.f, 0.f, 0.f, 0.f);
                bw[l * 2 + 1] = bw[l * 2];
            }
        }
    };
    auto writeB = [&](int buf) {
#pragma unroll
        for (int l = 0; l < 4; ++l) {
            const int cls = l * 32 + bcls;
            struct alignas(16) bf8s { __bf16 h[8]; };
            bf8s h;
            const float4 v0 = bw[l * 2], v1 = bw[l * 2 + 1];
            h.h[0] = (__bf16)v0.x; h.h[1] = (__bf16)v0.y; h.h[2] = (__bf16)v0.z; h.h[3] = (__bf16)v0.w;
            h.h[4] = (__bf16)v1.x; h.h[5] = (__bf16)v1.y; h.h[6] = (__bf16)v1.z; h.h[7] = (__bf16)v1.w;
            *reinterpret_cast<bf8s*>(lds + 32768 + buf * 16384 + cls * 128 +
                                     ((bqp ^ (cls & 7)) << 4)) = h;
        }
    };
    auto stageA = [&](int t, int buf) {
#pragma unroll
        for (int s = 0; s < 4; ++s) {
            const int row = s * 32 + wid * 8 + (lane >> 3);
            const int lc  = (lane & 7) ^ (row & 7);
            gload_lds16((const char*)xnb + (size_t)(r0 + row) * 1024 + t * 128 + lc * 16,
                        lds + buf * 16384 + s * 4096 + wid * 1024);
        }
    };
    f32x4 acc[4][4] = {};
    auto compute = [&](int buf) {
#pragma unroll
        for (int kk = 0; kk < 2; ++kk) {
            bf16x8 a[4], b[4];
            const int ck = (kk << 2) | lhi;
#pragma unroll
            for (int i = 0; i < 4; ++i) {
                const int r = wr * 64 + i * 16 + l15;
                a[i] = *reinterpret_cast<const bf16x8*>(lds + buf * 16384 + r * 128 + ((ck ^ (r & 7)) << 4));
            }
#pragma unroll
            for (int j = 0; j < 4; ++j) {
                const int cls = wc * 64 + j * 16 + l15;
                b[j] = *reinterpret_cast<const bf16x8*>(lds + 32768 + buf * 16384 + cls * 128 + ((ck ^ (cls & 7)) << 4));
            }
#pragma unroll
            for (int i = 0; i < 4; ++i)
#pragma unroll
                for (int j = 0; j < 4; ++j)
                    acc[i][j] = __builtin_amdgcn_mfma_f32_16x16x32_bf16(a[i], b[j], acc[i][j], 0, 0, 0);
        }
    };
    loadB(0);
    stageA(0, 0);
    writeB(0);
    __syncthreads();
#pragma unroll 1
    for (int t = 0; t < 8; ++t) {
        const int buf = t & 1;
        if (t + 1 < 8) { stageA(t + 1, buf ^ 1); loadB(t + 1); }
        compute(buf);
        if (t + 1 < 8) writeB(buf ^ 1);
        __syncthreads();
    }
#pragma unroll
    for (int i = 0; i < 4; ++i) {
#pragma unroll
        for (int r = 0; r < 4; ++r) {
            float v = 0.f;
#pragma unroll
            for (int j = 0; j < 4; ++j) {
                const int c = c0 + wc * 64 + j * 16 + l15;
                v += (c < NC) ? __expf(SSCALE * acc[i][j][r]) : 0.f;
            }
            v += __shfl_xor(v, 1);
            v += __shfl_xor(v, 2);
            v += __shfl_xor(v, 4);
            v += __shfl_xor(v, 8);
            if (l15 == 0) atomicAdd(&sums[r0 + wr * 64 + i * 16 + lhi * 4 + r], v);
        }
    }
}

__global__ void finalize_kernel(const float* __restrict__ sums, const float* __restrict__ tgt,
                                float* __restrict__ out) {
    const int tid  = threadIdx.x;
    const int wid  = tid >> 6;
    const int lane = tid & 63;
    float t  = tgt[tid];
    const float se = sums[tid];
    t = fminf(fmaxf(t, -1.0f + 1e-7f), 1.0f - 1e-7f);
    const float numer = SSCALE * cosf(acosf(t) + MMARGIN);
    const float excl  = se - expf(SSCALE * t);
    float L = numer - logf(expf(numer) + excl);
#pragma unroll
    for (int m = 1; m < 64; m <<= 1) L += __shfl_xor(L, m);
    __shared__ float ws2[16];
    if (lane == 0) ws2[wid] = L;
    __syncthreads();
    if (tid == 0) {
        float tot = 0.f;
        for (int i = 0; i < 16; ++i) tot += ws2[i];
        out[0] = -(tot / (float)NB);
    }
}

extern "C" void kernel_launch(void* const* d_in, const int* in_sizes, int n_in,
                              void* d_out, int out_size, void* d_ws, size_t ws_size,
                              hipStream_t stream) {
    const float* x      = (const float*)d_in[0];
    const int*   labels = (const int*)d_in[1];
    const float* W      = (const float*)d_in[2];
    float* out = (float*)d_out;

    char* wsb = (char*)d_ws;
    __bf16* xnb  = (__bf16*)wsb;                       // 1MB
    float*  sums = (float*)(wsb + 1048576);            // 4KB
    float*  tgt  = (float*)(wsb + 1052672);            // 4KB
    __bf16* Wbf  = (__bf16*)(wsb + 1056768);           // 102.5MB (NCPAD rows)
    const size_t WS_NEED = 1056768ull + (size_t)NCPAD * ND * 2;

    hipMemsetAsync(sums, 0, NB * sizeof(float), stream);
    prep_kernel<<<NB, 256, 0, stream>>>(x, xnb);
    target_kernel<<<NB / 4, 256, 0, stream>>>(xnb, W, labels, tgt);
    if (ws_size >= WS_NEED) {
        cvtw_kernel<<<((size_t)NCPAD * ND) / (256 * 8), 256, 0, stream>>>(W, Wbf);
        gemm_exp_kernel<<<GRIDSZ, 512, 0, stream>>>(xnb, Wbf, sums);
    } else {
        gemm_exp_fb<<<6256, 256, 0, stream>>>(xnb, W, sums);
    }
    finalize_kernel<<<1, 1024, 0, stream>>>(sums, tgt, out);
}